// Round 21
// baseline (57.208 us; speedup 1.0000x reference)
//
#include <hip/hip_runtime.h>

typedef _Float16 f16x8 __attribute__((ext_vector_type(8)));
typedef float f32x4 __attribute__((ext_vector_type(4)));

__device__ __forceinline__ f16x8 splat8(float v) {
  _Float16 h = (_Float16)v;
  return f16x8{h, h, h, h, h, h, h, h};
}

// XOR swizzle on f16-index for row-stride-64 tiles (16B-chunk granular)
__device__ __forceinline__ int swzh(int i) { return i ^ (((i >> 6) & 7) << 3); }

// ------- Kernel 1: x NCHW f32 -> xt NHWC f16 (1024 blks) + weight prep (216 blks) -------
__global__ __launch_bounds__(256) void k_xtprep(const float* __restrict__ x,
                                                const float* __restrict__ wt,
                                                const float* __restrict__ ow,
                                                _Float16* __restrict__ xt,
                                                _Float16* __restrict__ wb,
                                                _Float16* __restrict__ owb) {
  __shared__ float tile[64 * 65];
  int blk = blockIdx.x;
  int t = threadIdx.x;
  if (blk < 1024) {
    int b = blk >> 8;
    int y = (blk >> 1) & 127;
    int w0 = (blk & 1) * 64;
    const float* xp = x + ((size_t)(b * 64) * 128 + y) * 128 + w0;
#pragma unroll
    for (int it = 0; it < 4; ++it) {
      int idx = it * 256 + t;
      int c = idx >> 4, q = idx & 15;
      float4 v = *(const float4*)(xp + (size_t)c * 16384 + q * 4);
      float* tp = &tile[c * 65 + q * 4];
      tp[0] = v.x; tp[1] = v.y; tp[2] = v.z; tp[3] = v.w;
    }
    __syncthreads();
#pragma unroll
    for (int it = 0; it < 2; ++it) {
      int idx = it * 256 + t;
      int w = idx >> 3, c8 = idx & 7;
      f16x8 o;
#pragma unroll
      for (int j = 0; j < 8; ++j) o[j] = (_Float16)tile[(c8 * 8 + j) * 65 + w];
      *(f16x8*)&xt[(((size_t)b * 128 + y) * 128 + w0 + w) * 64 + c8 * 8] = o;
    }
  } else {
    int i = (blk - 1024) * 256 + t;
    if (i < 36864) {
      int k = i >> 12, rem = i & 4095, o = rem >> 6, c = rem & 63;
      wb[i] = (_Float16)wt[(o * 64 + c) * 9 + k];
    } else if (i < 36864 + 18432) {
      int j = i - 36864;
      int k = j >> 11, rem = j & 2047, o = rem >> 6, c = rem & 63;
      float v = (o < 18) ? ow[(o * 64 + c) * 9 + k] : 0.0f;
      owb[j] = (_Float16)v;
    }
  }
}

// ---------------- Kernel 2: fused deformable conv, producer-consumer ----------------
// grid 512 = (4 wtiles) x (32 h-quads) x (4 b), XCD swizzled; 512 threads (8 waves).
// Phase A: R16-proven (all waves). Phase B: WAVE SPECIALIZATION:
//   waves 0-3 = MFMA consumers (64o x 32px each, operands from LDS dbuf[k&1]);
//   waves 4-7 = samplers+W-stagers (fill dbuf[(k+1)&1]); ONE barrier per tap.
// FIX vs R20: Wt2 buffer stride is 4096 ELEMENTS (64x64 f16 tile), not 8192 —
// the 8192 stride overran into S2 buf0 (region corruption -> absmax 1.86).
__global__ __launch_bounds__(512, 2) void k_fused(
    const _Float16* __restrict__ xt, const _Float16* __restrict__ wb,
    const _Float16* __restrict__ owb, const float* __restrict__ ob,
    const float* __restrict__ bias, float* __restrict__ out) {
  // LDS 60,928 B -> 2 blocks/CU:
  //  Phase B: Wt2 2x[64][64] @0 (16,384) | S2 2x[128][64] @16,384 (32,768)
  //  Phase A: Xs [204][64] @0 (26,112) | owbL 2x[3][32][64] @26,112 (24,576)
  //  offL [128][20] f32 @50,688 (10,240) — disjoint from both phases' regions
  __shared__ char lds[60928];
  _Float16* Wt2 = (_Float16*)lds;
  _Float16* S2 = (_Float16*)(lds + 16384);
  _Float16* Xs = (_Float16*)lds;
  _Float16* owbL = (_Float16*)(lds + 26112);
  float* offL = (float*)(lds + 50688);

  int t = threadIdx.x;
  int lb = (blockIdx.x & 7) * 64 + (blockIdx.x >> 3);  // 512 = 8 XCDs x 64
  int w0 = (lb & 3) * 32;
  int h0 = ((lb >> 2) & 31) * 4;
  int b = lb >> 7;

  int lane = t & 63, wid = t >> 6;
  int lr = lane & 15, quad = lane >> 4;
  const _Float16* xb = xt + (size_t)b * 128 * 128 * 64;

  // ======= Stage0: Xs rows h0-1..h0+4 (6), px w0-1..w0+32 (34), 64c + owb batch0 =======
#pragma unroll
  for (int it = 0; it < 4; ++it) {
    int idx8 = it * 512 + t;  // 1632 chunks
    if (idx8 < 1632) {
      int c8 = idx8 & 7;
      int jr = idx8 >> 3;  // 0..203
      int col = jr % 34;
      int xr = jr / 34;
      int gy = h0 - 1 + xr;
      int gx = w0 - 1 + col;
      f16x8 v = {};
      if (((unsigned)gy < 128u) & ((unsigned)gx < 128u))
        v = *(const f16x8*)(xb + ((size_t)gy * 128 + gx) * 64 + c8 * 8);
      *(f16x8*)&Xs[swzh(jr * 64 + c8 * 8)] = v;
    }
  }
#pragma unroll
  for (int it = 0; it < 2; ++it) {  // owb taps 0..2 -> owbL buf0 (256 chunks/tap)
    int idx8 = it * 512 + t;
    if (idx8 < 768) {
      int kb = idx8 >> 8, rem = idx8 & 255;
      int o = rem >> 3, c8 = rem & 7;
      *(f16x8*)&owbL[swzh(kb * 2048 + o * 64 + c8 * 8)] =
          ((const f16x8*)(owb + kb * 2048))[rem];
    }
  }

  // ======= Phase A: offset conv (M=18pad32, N=128px, K=576), R16-proven =======
  {
    int oh = (wid >> 2) * 16;  // o-half base
    int ar = wid & 3;          // output row 0..3
    f32x4 accA[2];
    accA[0] = f32x4{0.f, 0.f, 0.f, 0.f};
    accA[1] = f32x4{0.f, 0.f, 0.f, 0.f};
#pragma unroll
    for (int bt = 0; bt < 3; ++bt) {
      __syncthreads();  // staging of batch bt complete
#pragma unroll
      for (int kb = 0; kb < 3; ++kb) {
        int ai = (bt & 1) * 6144 + kb * 2048 + (oh + lr) * 64 + quad * 8;
        f16x8 afr0 = *(const f16x8*)&owbL[swzh(ai)];
        f16x8 afr1 = *(const f16x8*)&owbL[swzh(ai + 32)];
#pragma unroll
        for (int ni = 0; ni < 2; ++ni) {
          int j = ni * 16 + lr + kb;  // 0..33
          int bi = ((ar + bt) * 34 + j) * 64 + quad * 8;
          f16x8 b0 = *(const f16x8*)&Xs[swzh(bi)];
          f16x8 b1 = *(const f16x8*)&Xs[swzh(bi + 32)];
          accA[ni] = __builtin_amdgcn_mfma_f32_16x16x32_f16(afr0, b0, accA[ni], 0, 0, 0);
          accA[ni] = __builtin_amdgcn_mfma_f32_16x16x32_f16(afr1, b1, accA[ni], 0, 0, 0);
        }
      }
      if (bt < 2) {  // stage batch bt+1 -> other buffer
#pragma unroll
        for (int it = 0; it < 2; ++it) {
          int idx8 = it * 512 + t;
          if (idx8 < 768) {
            int kb = idx8 >> 8, rem = idx8 & 255;
            int o = rem >> 3, c8 = rem & 7;
            *(f16x8*)&owbL[swzh(((bt + 1) & 1) * 6144 + kb * 2048 + o * 64 + c8 * 8)] =
                ((const f16x8*)(owb + ((bt + 1) * 3 + kb) * 2048))[rem];
          }
        }
      }
    }
    // offL disjoint from Xs/owbL; write directly
    int qr = quad * 4;
#pragma unroll
    for (int ni = 0; ni < 2; ++ni) {
#pragma unroll
      for (int r = 0; r < 4; ++r) {
        int co = oh + qr + r;
        if (co < 18) {
          int px = ar * 32 + ni * 16 + lr;
          offL[px * 20 + co] = accA[ni][r] + ob[co];
        }
      }
    }
  }
  __syncthreads();  // offL visible; Xs/owbL dead -> Wt2/S2 writable

  // ======= Phase B: producer-consumer =======
  // sampler (wid>=4): st in [0,256): px = st&127, chh = st>>7 (32-ch half)
  int st = t & 255;
  int pxS = st & 127, chh = st >> 7;
  int rS = pxS >> 5;
  int wS = w0 + (pxS & 31);
  // consumer (wid<4): wave owns all 64 o x 32 px (wpB)
  int wpB = (wid & 3) * 32;

  f32x4 acc[4][2];
#pragma unroll
  for (int i = 0; i < 4; ++i)
#pragma unroll
    for (int j = 0; j < 2; ++j) acc[i][j] = f32x4{0.f, 0.f, 0.f, 0.f};

#define STAGE_W_TAP(KK)                                                       \
  {                                                                           \
    const f16x8* wsrc = (const f16x8*)(wb + (KK) * 4096);                     \
    _Pragma("unroll") for (int it = 0; it < 2; ++it) {                        \
      int idx8 = it * 256 + st;                                               \
      int o = idx8 >> 3, c8 = idx8 & 7;                                       \
      *(f16x8*)&Wt2[((KK) & 1) * 4096 + swzh(o * 64 + c8 * 8)] = wsrc[idx8];  \
    }                                                                         \
  }

#define SAMPLE_TAP(KK)                                                        \
  {                                                                           \
    int ki = (KK) / 3, kj = (KK) % 3;                                         \
    float dy = offL[pxS * 20 + 2 * (KK)];                                     \
    float dx = offL[pxS * 20 + 2 * (KK) + 1];                                 \
    float py = dy + (float)(h0 + rS + ki - 1);                                \
    float pxf = dx + (float)(wS + kj - 1);                                    \
    float fy = floorf(py), fx = floorf(pxf);                                  \
    float ly = py - fy, lx = pxf - fx;                                        \
    int y0 = (int)fy, x0 = (int)fx;                                           \
    int y1 = y0 + 1, x1 = x0 + 1;                                             \
    bool vy0 = (unsigned)y0 < 128u, vy1 = (unsigned)y1 < 128u;                \
    bool vx0 = (unsigned)x0 < 128u, vx1 = (unsigned)x1 < 128u;                \
    float w00 = (vy0 && vx0) ? (1.f - ly) * (1.f - lx) : 0.f;                 \
    float w01 = (vy0 && vx1) ? (1.f - ly) * lx : 0.f;                         \
    float w10 = (vy1 && vx0) ? ly * (1.f - lx) : 0.f;                         \
    float w11 = (vy1 && vx1) ? ly * lx : 0.f;                                 \
    int yc0 = min(max(y0, 0), 127), yc1 = min(max(y1, 0), 127);               \
    int xc0 = min(max(x0, 0), 127), xc1 = min(max(x1, 0), 127);               \
    const _Float16* p00 = xb + (yc0 * 128 + xc0) * 64 + chh * 32;             \
    int dxo = (xc1 - xc0) * 64, dyo = (yc1 - yc0) * 8192;                     \
    f16x8 g0[4], g1[4], g2[4], g3[4];                                         \
    _Pragma("unroll") for (int j = 0; j < 4; ++j) {                           \
      g0[j] = *(const f16x8*)(p00 + j * 8);                                   \
      g1[j] = *(const f16x8*)(p00 + dxo + j * 8);                             \
      g2[j] = *(const f16x8*)(p00 + dyo + j * 8);                             \
      g3[j] = *(const f16x8*)(p00 + dyo + dxo + j * 8);                       \
    }                                                                         \
    f16x8 W00 = splat8(w00), W01 = splat8(w01);                               \
    f16x8 W10 = splat8(w10), W11 = splat8(w11);                               \
    _Float16* Sd = (_Float16*)&S2[((KK) & 1) * 8192];                         \
    _Pragma("unroll") for (int j = 0; j < 4; ++j) {                           \
      f16x8 s = W00 * g0[j] + W01 * g1[j] + W10 * g2[j] + W11 * g3[j];        \
      *(f16x8*)&Sd[swzh(pxS * 64 + chh * 32 + j * 8)] = s;                    \
    }                                                                         \
  }

  // prologue: samplers fill tap-0 buffers; consumers wait at barrier
  if (wid >= 4) {
    STAGE_W_TAP(0)
    SAMPLE_TAP(0)
  }
  __syncthreads();

#pragma unroll
  for (int k = 0; k < 9; ++k) {
    if (wid < 4) {
      // ---- consume tap k: 16 MFMA, operands from dbuf[k&1] ----
      const _Float16* Wc = &Wt2[(k & 1) * 4096];
      const _Float16* Sc = &S2[(k & 1) * 8192];
#pragma unroll
      for (int ks = 0; ks < 2; ++ks) {
        int c0 = ks * 32 + quad * 8;
        f16x8 bfr[2], afr[4];
#pragma unroll
        for (int ni = 0; ni < 2; ++ni)
          bfr[ni] = *(const f16x8*)&Sc[swzh((wpB + ni * 16 + lr) * 64 + c0)];
#pragma unroll
        for (int mi = 0; mi < 4; ++mi)
          afr[mi] = *(const f16x8*)&Wc[swzh((mi * 16 + lr) * 64 + c0)];
#pragma unroll
        for (int mi = 0; mi < 4; ++mi)
#pragma unroll
          for (int ni = 0; ni < 2; ++ni)
            acc[mi][ni] = __builtin_amdgcn_mfma_f32_16x16x32_f16(
                afr[mi], bfr[ni], acc[mi][ni], 0, 0, 0);
      }
    } else if (k < 8) {
      // ---- produce tap k+1 into dbuf[(k+1)&1] (overlaps consumers' MFMA) ----
      switch (k + 1) {
        case 1: STAGE_W_TAP(1) SAMPLE_TAP(1) break;
        case 2: STAGE_W_TAP(2) SAMPLE_TAP(2) break;
        case 3: STAGE_W_TAP(3) SAMPLE_TAP(3) break;
        case 4: STAGE_W_TAP(4) SAMPLE_TAP(4) break;
        case 5: STAGE_W_TAP(5) SAMPLE_TAP(5) break;
        case 6: STAGE_W_TAP(6) SAMPLE_TAP(6) break;
        case 7: STAGE_W_TAP(7) SAMPLE_TAP(7) break;
        case 8: STAGE_W_TAP(8) SAMPLE_TAP(8) break;
      }
    }
    __syncthreads();  // uniform: tap k consumed; tap k+1 buffers ready
  }
#undef SAMPLE_TAP
#undef STAGE_W_TAP

  // ---- epilogue (consumers only): col=lane&15, row=quad*4+r ----
  if (wid < 4) {
    int col = lane & 15;
    int qr = quad * 4;
#pragma unroll
    for (int mi = 0; mi < 4; ++mi) {
#pragma unroll
      for (int ni = 0; ni < 2; ++ni) {
#pragma unroll
        for (int r = 0; r < 4; ++r) {
          int o = mi * 16 + qr + r;
          int px = wpB + ni * 16 + col;  // 0..127
          out[(((size_t)b * 64 + o) * 128 + h0 + (px >> 5)) * 128 + w0 + (px & 31)] =
              acc[mi][ni][r] + bias[o];
        }
      }
    }
  }
}

extern "C" void kernel_launch(void* const* d_in, const int* in_sizes, int n_in,
                              void* d_out, int out_size, void* d_ws,
                              size_t ws_size, hipStream_t stream) {
  const float* x = (const float*)d_in[0];       // (4,64,128,128)
  const float* ow = (const float*)d_in[1];      // (18,64,3,3)
  const float* ob = (const float*)d_in[2];      // (18,)
  const float* wt = (const float*)d_in[3];      // (64,64,3,3)
  const float* bias = (const float*)d_in[4];    // (64,)
  float* out = (float*)d_out;                   // (4,64,128,128)

  char* ws = (char*)d_ws;
  _Float16* xt = (_Float16*)ws;                      // 8,388,608 B
  _Float16* wb = (_Float16*)(ws + 8388608);          // 73,728 B
  _Float16* owb = (_Float16*)(ws + 8388608 + 73728); // 36,864 B

  k_xtprep<<<1240, 256, 0, stream>>>(x, wt, ow, xt, wb, owb);
  k_fused<<<512, 512, 0, stream>>>(xt, wb, owb, ob, bias, out);
}

// Round 22
// 35.755 us; speedup vs baseline: 1.6000x; 1.6000x over previous
//
#include <hip/hip_runtime.h>

typedef _Float16 f16x8 __attribute__((ext_vector_type(8)));
typedef float f32x4 __attribute__((ext_vector_type(4)));

__device__ __forceinline__ f16x8 splat8(float v) {
  _Float16 h = (_Float16)v;
  return f16x8{h, h, h, h, h, h, h, h};
}

// XOR swizzle on f16-index for row-stride-64 tiles (16B-chunk granular)
__device__ __forceinline__ int swzh(int i) { return i ^ (((i >> 6) & 7) << 3); }

// ------- Kernel 1: x NCHW f32 -> xt NHWC f16 (1024 blks) + weight prep (216 blks) -------
__global__ __launch_bounds__(256) void k_xtprep(const float* __restrict__ x,
                                                const float* __restrict__ wt,
                                                const float* __restrict__ ow,
                                                _Float16* __restrict__ xt,
                                                _Float16* __restrict__ wb,
                                                _Float16* __restrict__ owb) {
  __shared__ float tile[64 * 65];
  int blk = blockIdx.x;
  int t = threadIdx.x;
  if (blk < 1024) {
    int b = blk >> 8;
    int y = (blk >> 1) & 127;
    int w0 = (blk & 1) * 64;
    const float* xp = x + ((size_t)(b * 64) * 128 + y) * 128 + w0;
#pragma unroll
    for (int it = 0; it < 4; ++it) {
      int idx = it * 256 + t;
      int c = idx >> 4, q = idx & 15;
      float4 v = *(const float4*)(xp + (size_t)c * 16384 + q * 4);
      float* tp = &tile[c * 65 + q * 4];
      tp[0] = v.x; tp[1] = v.y; tp[2] = v.z; tp[3] = v.w;
    }
    __syncthreads();
#pragma unroll
    for (int it = 0; it < 2; ++it) {
      int idx = it * 256 + t;
      int w = idx >> 3, c8 = idx & 7;
      f16x8 o;
#pragma unroll
      for (int j = 0; j < 8; ++j) o[j] = (_Float16)tile[(c8 * 8 + j) * 65 + w];
      *(f16x8*)&xt[(((size_t)b * 128 + y) * 128 + w0 + w) * 64 + c8 * 8] = o;
    }
  } else {
    int i = (blk - 1024) * 256 + t;
    if (i < 36864) {
      int k = i >> 12, rem = i & 4095, o = rem >> 6, c = rem & 63;
      wb[i] = (_Float16)wt[(o * 64 + c) * 9 + k];
    } else if (i < 36864 + 18432) {
      int j = i - 36864;
      int k = j >> 11, rem = j & 2047, o = rem >> 6, c = rem & 63;
      float v = (o < 18) ? ow[(o * 64 + c) * 9 + k] : 0.0f;
      owb[j] = (_Float16)v;
    }
  }
}

// ---------------- Kernel 2: fused deformable conv, 4h x 32px tiles ----------------
// grid 512 = (4 wtiles) x (32 h-quads) x (4 b), XCD swizzled; 512 threads (8 waves).
// Best-measured configuration (R16/R19, 35.8us reproduced): W3 batches
// dbuf-staged one batch ahead (k=1,4); S single-buf 2-bar/tap; all MFMA
// operands from LDS; 2 blocks/CU.
__global__ __launch_bounds__(512, 2) void k_fused(
    const _Float16* __restrict__ xt, const _Float16* __restrict__ wb,
    const _Float16* __restrict__ owb, const float* __restrict__ ob,
    const float* __restrict__ bias, float* __restrict__ out) {
  // LDS 75,776 B -> 2 blocks/CU:
  //  Phase B: Wp3 2x[3][64][64] @0 (49,152) | S [128][64] @49,152 (16,384)
  //  Phase A: Xs [204][64] @0 (26,112) | owbL 2x[3][32][64] @26,112 (24,576)
  //  offL [128][20] f32 @65,536 (10,240) — disjoint
  __shared__ char lds[75776];
  _Float16* Wp3 = (_Float16*)lds;
  _Float16* S = (_Float16*)(lds + 49152);
  _Float16* Xs = (_Float16*)lds;
  _Float16* owbL = (_Float16*)(lds + 26112);
  float* offL = (float*)(lds + 65536);

  int t = threadIdx.x;
  int lb = (blockIdx.x & 7) * 64 + (blockIdx.x >> 3);  // 512 = 8 XCDs x 64
  int w0 = (lb & 3) * 32;
  int h0 = ((lb >> 2) & 31) * 4;
  int b = lb >> 7;

  int lane = t & 63, wid = t >> 6;
  int lr = lane & 15, quad = lane >> 4;
  const _Float16* xb = xt + (size_t)b * 128 * 128 * 64;

  // ======= Stage0: Xs rows h0-1..h0+4 (6), px w0-1..w0+32 (34), 64c + owb batch0 =======
#pragma unroll
  for (int it = 0; it < 4; ++it) {
    int idx8 = it * 512 + t;  // 1632 chunks
    if (idx8 < 1632) {
      int c8 = idx8 & 7;
      int jr = idx8 >> 3;  // 0..203
      int col = jr % 34;
      int xr = jr / 34;
      int gy = h0 - 1 + xr;
      int gx = w0 - 1 + col;
      f16x8 v = {};
      if (((unsigned)gy < 128u) & ((unsigned)gx < 128u))
        v = *(const f16x8*)(xb + ((size_t)gy * 128 + gx) * 64 + c8 * 8);
      *(f16x8*)&Xs[swzh(jr * 64 + c8 * 8)] = v;
    }
  }
#pragma unroll
  for (int it = 0; it < 2; ++it) {  // owb taps 0..2 -> owbL buf0 (256 chunks/tap)
    int idx8 = it * 512 + t;
    if (idx8 < 768) {
      int kb = idx8 >> 8, rem = idx8 & 255;
      int o = rem >> 3, c8 = rem & 7;
      *(f16x8*)&owbL[swzh(kb * 2048 + o * 64 + c8 * 8)] =
          ((const f16x8*)(owb + kb * 2048))[rem];
    }
  }

  // ======= Phase A: offset conv (M=18pad32, N=128px, K=576), 4 barriers =======
  {
    int oh = (wid >> 2) * 16;  // o-half base
    int ar = wid & 3;          // output row 0..3
    f32x4 accA[2];
    accA[0] = f32x4{0.f, 0.f, 0.f, 0.f};
    accA[1] = f32x4{0.f, 0.f, 0.f, 0.f};
#pragma unroll
    for (int bt = 0; bt < 3; ++bt) {
      __syncthreads();  // staging of batch bt complete
#pragma unroll
      for (int kb = 0; kb < 3; ++kb) {
        int ai = (bt & 1) * 6144 + kb * 2048 + (oh + lr) * 64 + quad * 8;
        f16x8 afr0 = *(const f16x8*)&owbL[swzh(ai)];
        f16x8 afr1 = *(const f16x8*)&owbL[swzh(ai + 32)];
#pragma unroll
        for (int ni = 0; ni < 2; ++ni) {
          int j = ni * 16 + lr + kb;  // 0..33
          int bi = ((ar + bt) * 34 + j) * 64 + quad * 8;
          f16x8 b0 = *(const f16x8*)&Xs[swzh(bi)];
          f16x8 b1 = *(const f16x8*)&Xs[swzh(bi + 32)];
          accA[ni] = __builtin_amdgcn_mfma_f32_16x16x32_f16(afr0, b0, accA[ni], 0, 0, 0);
          accA[ni] = __builtin_amdgcn_mfma_f32_16x16x32_f16(afr1, b1, accA[ni], 0, 0, 0);
        }
      }
      if (bt < 2) {  // stage batch bt+1 -> other buffer (overlaps other waves' MFMA)
#pragma unroll
        for (int it = 0; it < 2; ++it) {
          int idx8 = it * 512 + t;
          if (idx8 < 768) {
            int kb = idx8 >> 8, rem = idx8 & 255;
            int o = rem >> 3, c8 = rem & 7;
            *(f16x8*)&owbL[swzh(((bt + 1) & 1) * 6144 + kb * 2048 + o * 64 + c8 * 8)] =
                ((const f16x8*)(owb + ((bt + 1) * 3 + kb) * 2048))[rem];
          }
        }
      }
    }
    // offL disjoint; write directly
    int qr = quad * 4;
#pragma unroll
    for (int ni = 0; ni < 2; ++ni) {
#pragma unroll
      for (int r = 0; r < 4; ++r) {
        int co = oh + qr + r;
        if (co < 18) {
          int px = ar * 32 + ni * 16 + lr;
          offL[px * 20 + co] = accA[ni][r] + ob[co];
        }
      }
    }
  }
  __syncthreads();  // offL visible; Xs/owbL dead -> Wp3/S writable

  // ======= Phase B: main conv (64o x 128px, K=576) =======
  int pixS = t >> 2, cg = t & 3;  // sampler: 128 px x 4 ch-groups of 16
  int rS = pixS >> 5;
  int wS = w0 + (pixS & 31);
  int woB = (wid >> 2) * 32, wpB = (wid & 3) * 32;

  f32x4 acc[2][2];
#pragma unroll
  for (int i = 0; i < 2; ++i)
#pragma unroll
    for (int j = 0; j < 2; ++j) acc[i][j] = f32x4{0.f, 0.f, 0.f, 0.f};

  // prologue: stage W batch0 -> Wp3 buf0 (512 chunks/tap, 1536 total)
#pragma unroll
  for (int it = 0; it < 3; ++it) {
    int idx8 = it * 512 + t;  // 0..1535 = 3 taps x 64o x 8c8, exact
    int kb = idx8 >> 9, rem = idx8 & 511;
    int o = rem >> 3, c8 = rem & 7;
    *(f16x8*)&Wp3[swzh(kb * 4096 + o * 64 + c8 * 8)] =
        ((const f16x8*)(wb + kb * 4096))[rem];
  }

#pragma unroll
  for (int k = 0; k < 9; ++k) {
    // stage W batch (k/3)+1 one batch ahead, at k=1 and k=4 (512 chunks/tap)
    if (k == 1 || k == 4) {
      int bt = k / 3 + 1;
#pragma unroll
      for (int it = 0; it < 3; ++it) {
        int idx8 = it * 512 + t;  // 0..1535
        int kb = idx8 >> 9, rem = idx8 & 511;
        int o = rem >> 3, c8 = rem & 7;
        *(f16x8*)&Wp3[swzh((bt & 1) * 12288 + kb * 4096 + o * 64 + c8 * 8)] =
            ((const f16x8*)(wb + (bt * 3 + kb) * 4096))[rem];
      }
    }
    // ---- sample tap k: 8 gathers + f16 interp -> S[pixS][cg*16..+16] ----
    {
      int ki = k / 3, kj = k % 3;
      float dy = offL[pixS * 20 + 2 * k];
      float dx = offL[pixS * 20 + 2 * k + 1];
      float py = dy + (float)(h0 + rS + ki - 1);
      float pxf = dx + (float)(wS + kj - 1);
      float fy = floorf(py), fx = floorf(pxf);
      float ly = py - fy, lx = pxf - fx;
      int y0 = (int)fy, x0 = (int)fx;
      int y1 = y0 + 1, x1 = x0 + 1;
      bool vy0 = (unsigned)y0 < 128u, vy1 = (unsigned)y1 < 128u;
      bool vx0 = (unsigned)x0 < 128u, vx1 = (unsigned)x1 < 128u;
      float w00 = (vy0 && vx0) ? (1.f - ly) * (1.f - lx) : 0.f;
      float w01 = (vy0 && vx1) ? (1.f - ly) * lx : 0.f;
      float w10 = (vy1 && vx0) ? ly * (1.f - lx) : 0.f;
      float w11 = (vy1 && vx1) ? ly * lx : 0.f;
      int yc0 = min(max(y0, 0), 127), yc1 = min(max(y1, 0), 127);
      int xc0 = min(max(x0, 0), 127), xc1 = min(max(x1, 0), 127);
      const _Float16* p00 = xb + (yc0 * 128 + xc0) * 64 + cg * 16;
      int dxo = (xc1 - xc0) * 64, dyo = (yc1 - yc0) * 8192;
      f16x8 ga0 = *(const f16x8*)(p00);
      f16x8 ga1 = *(const f16x8*)(p00 + 8);
      f16x8 gb0 = *(const f16x8*)(p00 + dxo);
      f16x8 gb1 = *(const f16x8*)(p00 + dxo + 8);
      f16x8 gc0 = *(const f16x8*)(p00 + dyo);
      f16x8 gc1 = *(const f16x8*)(p00 + dyo + 8);
      f16x8 gd0 = *(const f16x8*)(p00 + dyo + dxo);
      f16x8 gd1 = *(const f16x8*)(p00 + dyo + dxo + 8);
      f16x8 W00 = splat8(w00), W01 = splat8(w01);
      f16x8 W10 = splat8(w10), W11 = splat8(w11);
      f16x8 s0 = W00 * ga0 + W01 * gb0 + W10 * gc0 + W11 * gd0;
      f16x8 s1 = W00 * ga1 + W01 * gb1 + W10 * gc1 + W11 * gd1;
      int si = pixS * 64 + cg * 16;
      *(f16x8*)&S[swzh(si)] = s0;
      *(f16x8*)&S[swzh(si + 8)] = s1;
    }
    __syncthreads();  // S (and any pending W batch) ready
    // ---- MFMA tap k: A from Wp3 (resident batch), B from S ----
    {
      int wo = ((k / 3) & 1) * 12288 + (k % 3) * 4096;
#pragma unroll
      for (int ks = 0; ks < 2; ++ks) {
        int c0 = ks * 32 + quad * 8;
        f16x8 bfr[2], afr[2];
#pragma unroll
        for (int ni = 0; ni < 2; ++ni)
          bfr[ni] = *(const f16x8*)&S[swzh((wpB + ni * 16 + lr) * 64 + c0)];
#pragma unroll
        for (int mi = 0; mi < 2; ++mi)
          afr[mi] = *(const f16x8*)&Wp3[swzh(wo + (woB + mi * 16 + lr) * 64 + c0)];
#pragma unroll
        for (int mi = 0; mi < 2; ++mi)
#pragma unroll
          for (int ni = 0; ni < 2; ++ni)
            acc[mi][ni] = __builtin_amdgcn_mfma_f32_16x16x32_f16(
                afr[mi], bfr[ni], acc[mi][ni], 0, 0, 0);
      }
    }
    if (k < 8) __syncthreads();  // before next tap overwrites S
  }

  // ---- epilogue: col=lane&15 (px within 16-tile), row=quad*4+r (o) ----
  {
    int col = lane & 15;
    int qr = quad * 4;
#pragma unroll
    for (int mi = 0; mi < 2; ++mi) {
#pragma unroll
      for (int ni = 0; ni < 2; ++ni) {
#pragma unroll
        for (int r = 0; r < 4; ++r) {
          int o = woB + mi * 16 + qr + r;
          int px = wpB + ni * 16 + col;  // 0..127
          out[(((size_t)b * 64 + o) * 128 + h0 + (px >> 5)) * 128 + w0 + (px & 31)] =
              acc[mi][ni][r] + bias[o];
        }
      }
    }
  }
}

extern "C" void kernel_launch(void* const* d_in, const int* in_sizes, int n_in,
                              void* d_out, int out_size, void* d_ws,
                              size_t ws_size, hipStream_t stream) {
  const float* x = (const float*)d_in[0];       // (4,64,128,128)
  const float* ow = (const float*)d_in[1];      // (18,64,3,3)
  const float* ob = (const float*)d_in[2];      // (18,)
  const float* wt = (const float*)d_in[3];      // (64,64,3,3)
  const float* bias = (const float*)d_in[4];    // (64,)
  float* out = (float*)d_out;                   // (4,64,128,128)

  char* ws = (char*)d_ws;
  _Float16* xt = (_Float16*)ws;                      // 8,388,608 B
  _Float16* wb = (_Float16*)(ws + 8388608);          // 73,728 B
  _Float16* owb = (_Float16*)(ws + 8388608 + 73728); // 36,864 B

  k_xtprep<<<1240, 256, 0, stream>>>(x, wt, ow, xt, wb, owb);
  k_fused<<<512, 512, 0, stream>>>(xt, wb, owb, ob, bias, out);
}